// Round 1
// baseline (65976.520 us; speedup 1.0000x reference)
//
#include <hip/hip_runtime.h>
#include <hip/hip_bf16.h>
#include <cstddef>

// ---------------- problem constants ----------------
constexpr int B_ = 64, T_ = 512, E_ = 768, H_ = 512, G_ = 1536, NF_ = 256;

// ---------------- workspace layout (bytes) ----------------
// Region A [0, 192MB): gi_c f32; later reused: gi0/gi1 bf16 at [0,96MB),
//                      out0/out1 f32 at [96MB,160MB).
constexpr size_t SZ_GIC   = (size_t)B_ * T_ * G_ * 4;       // 201326592
constexpr size_t OFF_GI   = 0;
constexpr size_t OFF_OUT  = (size_t)B_ * T_ * G_ * 2;       // 100663296 (after bf16 gi)
constexpr size_t OFF_MISC = SZ_GIC;
constexpr size_t OFF_H0   = OFF_MISC;
constexpr size_t OFF_H1   = OFF_H0 + (size_t)B_ * H_ * 4;
constexpr size_t OFF_SEL  = OFF_H1 + (size_t)B_ * H_ * 4;
constexpr size_t OFF_ORD  = OFF_SEL + (size_t)B_ * T_ * 4;
constexpr size_t OFF_NSEL = OFF_ORD + (size_t)B_ * T_ * 4;
constexpr size_t OFF_MAXN = OFF_NSEL + 256;
constexpr size_t OFF_CNT  = OFF_MAXN + 256;
constexpr size_t OFF_POOL = OFF_CNT + 256;
constexpr size_t WS_NEED  = OFF_POOL + (size_t)B_ * 3 * NF_ * 4;

// =====================================================================
// Tiled fp32 GEMM: C[m][n] = sum_k Arow(m)[k]*W[n][k] + bias[n]
// AMODE: 0 = flat rows (arow = A + m*ldA)
//        1 = gather rows (arow = A + (b*T + order[b*T+t])*ldA, scaled by t<nsel[b])
//        2 = conv windows (arow = A + (b*T + t)*H, K = k*H contiguous)
// OMODE: 0 = f32 store, 1 = bf16 store, 2 = relu+bias+time-max -> atomicMax pool
// grid.x tiles M (per-batch tiled for AMODE 1/2), grid.y tiles N. block = 256.
// =====================================================================
template<int AMODE, int OMODE>
__global__ __launch_bounds__(256) void gemm_k(
    const float* __restrict__ A, const float* __restrict__ W,
    const float* __restrict__ bias,
    float* __restrict__ Cf, __hip_bfloat16* __restrict__ Cb,
    unsigned int* __restrict__ pool,
    int N, int K, int ldA, int rowsPerB, int tilesPerB,
    const int* __restrict__ order, const int* __restrict__ nsel, int poolOff)
{
    __shared__ float As[64 * 20];
    __shared__ float Bs[64 * 20];
    __shared__ const float* rowp[64];
    __shared__ float rowsc[64];

    const int tid = threadIdx.x;
    const int tx = tid & 15, ty = tid >> 4;
    const int bx = blockIdx.x;
    const int n0 = blockIdx.y * 64;

    int tileb = 0, tilet0 = 0;
    if (AMODE != 0) { tileb = bx / tilesPerB; tilet0 = (bx % tilesPerB) * 64; }

    if (tid < 64) {
        const float* p = nullptr; float sc = 1.f;
        if (AMODE == 0) {
            p = A + ((size_t)bx * 64 + tid) * (size_t)ldA;
        } else if (AMODE == 1) {
            int t = tilet0 + tid;
            int src = order[tileb * T_ + t];
            p = A + ((size_t)tileb * T_ + src) * (size_t)ldA;
            sc = (t < nsel[tileb]) ? 1.f : 0.f;
        } else {
            int t = tilet0 + tid;
            if (t < rowsPerB) p = A + ((size_t)tileb * T_ + t) * (size_t)H_;
        }
        rowp[tid] = p; rowsc[tid] = sc;
    }
    __syncthreads();

    float acc[4][4] = {};
    const int rl = tid >> 2, kl = (tid & 3) * 4;
    const float* __restrict__ ap = rowp[rl];
    const float  asc = rowsc[rl];
    const float* __restrict__ wrow = W + (size_t)(n0 + rl) * (size_t)K + kl;

    for (int k0 = 0; k0 < K; k0 += 16) {
        float4 av = make_float4(0.f, 0.f, 0.f, 0.f);
        if (ap) av = *(const float4*)(ap + k0 + kl);
        float4 wv = *(const float4*)(wrow + k0);
        __syncthreads();   // prior compute done before overwriting LDS
        As[rl*20+kl+0] = av.x * asc; As[rl*20+kl+1] = av.y * asc;
        As[rl*20+kl+2] = av.z * asc; As[rl*20+kl+3] = av.w * asc;
        Bs[rl*20+kl+0] = wv.x; Bs[rl*20+kl+1] = wv.y;
        Bs[rl*20+kl+2] = wv.z; Bs[rl*20+kl+3] = wv.w;
        __syncthreads();
        #pragma unroll
        for (int kk = 0; kk < 16; ++kk) {
            float a0 = As[(ty*4+0)*20+kk], a1 = As[(ty*4+1)*20+kk];
            float a2 = As[(ty*4+2)*20+kk], a3 = As[(ty*4+3)*20+kk];
            float w0 = Bs[(tx*4+0)*20+kk], w1 = Bs[(tx*4+1)*20+kk];
            float w2 = Bs[(tx*4+2)*20+kk], w3 = Bs[(tx*4+3)*20+kk];
            acc[0][0]=fmaf(a0,w0,acc[0][0]); acc[0][1]=fmaf(a0,w1,acc[0][1]);
            acc[0][2]=fmaf(a0,w2,acc[0][2]); acc[0][3]=fmaf(a0,w3,acc[0][3]);
            acc[1][0]=fmaf(a1,w0,acc[1][0]); acc[1][1]=fmaf(a1,w1,acc[1][1]);
            acc[1][2]=fmaf(a1,w2,acc[1][2]); acc[1][3]=fmaf(a1,w3,acc[1][3]);
            acc[2][0]=fmaf(a2,w0,acc[2][0]); acc[2][1]=fmaf(a2,w1,acc[2][1]);
            acc[2][2]=fmaf(a2,w2,acc[2][2]); acc[2][3]=fmaf(a2,w3,acc[2][3]);
            acc[3][0]=fmaf(a3,w0,acc[3][0]); acc[3][1]=fmaf(a3,w1,acc[3][1]);
            acc[3][2]=fmaf(a3,w2,acc[3][2]); acc[3][3]=fmaf(a3,w3,acc[3][3]);
        }
    }

    if (OMODE == 0 || OMODE == 1) {
        #pragma unroll
        for (int i = 0; i < 4; ++i) {
            int m;
            if (AMODE == 0) m = bx * 64 + ty*4 + i;
            else            m = tileb * T_ + tilet0 + ty*4 + i;
            size_t co = (size_t)m * (size_t)N + n0 + tx*4;
            #pragma unroll
            for (int j = 0; j < 4; ++j) {
                float v = acc[i][j] + bias[n0 + tx*4 + j];
                if (OMODE == 0) Cf[co + j] = v;
                else            Cb[co + j] = __float2bfloat16(v);
            }
        }
    } else {
        // conv epilogue: relu(acc+bias), max over valid rows of this tile
        float mx[4] = {0.f, 0.f, 0.f, 0.f};
        #pragma unroll
        for (int i = 0; i < 4; ++i) {
            int t = tilet0 + ty*4 + i;
            bool v = t < rowsPerB;
            #pragma unroll
            for (int j = 0; j < 4; ++j) {
                float val = fmaxf(acc[i][j] + bias[n0 + tx*4 + j], 0.f);
                if (v) mx[j] = fmaxf(mx[j], val);
            }
        }
        __syncthreads();  // reuse As as reduction buffer
        #pragma unroll
        for (int j = 0; j < 4; ++j) As[(tx*4+j)*17 + ty] = mx[j];
        __syncthreads();
        if (tid < 64) {
            float m = 0.f;
            #pragma unroll
            for (int q = 0; q < 16; ++q) m = fmaxf(m, As[tid*17 + q]);
            atomicMax(&pool[(size_t)tileb * (3*NF_) + poolOff + n0 + tid],
                      __float_as_uint(m));  // relu values >= 0: uint-ordered
        }
    }
}

// =====================================================================
// GRU recurrence, hidden-sliced across 64 WGs (8 units each), all 64
// batches per WG. h ping-pong in global, transposed [k][b]. Grid barrier
// via device-scope atomics (64 WGs always co-resident on 256 CUs).
// SEL: also computes sel[b][t] = (h(t+1) @ (Ws[1]-Ws[0]) + (bs1-bs0)) > 0
// from the staged full-h one step later (extra dot-only iteration at end).
// LAYER: masked update (t < nsel[b]), writes valid outputs only (out pre-zeroed).
// =====================================================================
template<bool SEL>
__global__ __launch_bounds__(256) void rec_k(
    const float* __restrict__ giF, const __hip_bfloat16* __restrict__ giB,
    const float* __restrict__ Whh, const float* __restrict__ bhh,
    const float* __restrict__ Ws, const float* __restrict__ bs,
    const int* __restrict__ nselp, const int* __restrict__ maxnp,
    float* __restrict__ h0, float* __restrict__ h1,
    float* __restrict__ outp, int* __restrict__ selp,
    int* __restrict__ cnt)
{
    __shared__ float hs[128 * 64];          // 32KB: one k-chunk of full h (transposed)
    const int tid = threadIdx.x;
    const int b = tid & 63;
    const int u = __builtin_amdgcn_readfirstlane(tid >> 6);   // wave id 0..3
    const int i0 = blockIdx.x * 8 + 2 * u;                    // 2 hidden units per thread

    const float* __restrict__ wA = Whh + (size_t)(i0        ) * H_;   // r, unit0
    const float* __restrict__ wB = Whh + (size_t)(i0 + 1    ) * H_;   // r, unit1
    const float* __restrict__ wC = Whh + (size_t)(H_ + i0   ) * H_;   // z, unit0
    const float* __restrict__ wD = Whh + (size_t)(H_ + i0 +1) * H_;   // z, unit1
    const float* __restrict__ wE = Whh + (size_t)(2*H_ + i0 ) * H_;   // n, unit0
    const float* __restrict__ wF = Whh + (size_t)(2*H_+i0 +1) * H_;   // n, unit1
    const float bhR0 = bhh[i0],      bhR1 = bhh[i0+1];
    const float bhZ0 = bhh[H_+i0],   bhZ1 = bhh[H_+i0+1];
    const float bhN0 = bhh[2*H_+i0], bhN1 = bhh[2*H_+i0+1];

    const int ns = SEL ? 0 : nselp[b];
    const int NT = SEL ? T_ : *maxnp;
    const float db = SEL ? (bs[1] - bs[0]) : 0.f;
    const int TOTAL = SEL ? (T_ + 1) : NT;

    int gen = 0;
    for (int t = 0; t < TOTAL; ++t) {
        const bool last = SEL && (t == T_);
        const float* hcur = (t & 1) ? h1 : h0;
        float* hnxt = (t & 1) ? h0 : h1;

        float aR0=bhR0, aR1=bhR1, aZ0=bhZ0, aZ1=bhZ1, aN0=bhN0, aN1=bhN1;
        float dot = 0.f;

        for (int q = 0; q < 4; ++q) {       // 4 k-chunks of 128
            const int k0 = q * 128;
            __syncthreads();                // prior chunk's readers done
            #pragma unroll
            for (int i = 0; i < 8; ++i) {   // stage 8KB chunk, coalesced float4
                const int f = i * 1024 + tid * 4;
                *(float4*)(hs + f) = *(const float4*)(hcur + (size_t)k0 * 64 + f);
            }
            __syncthreads();
            if (!last) {
                #pragma unroll 4
                for (int kk = 0; kk < 128; ++kk) {
                    const float hv = hs[kk * 64 + b];
                    const int k = k0 + kk;
                    aR0 = fmaf(hv, wA[k], aR0);
                    aR1 = fmaf(hv, wB[k], aR1);
                    aZ0 = fmaf(hv, wC[k], aZ0);
                    aZ1 = fmaf(hv, wD[k], aZ1);
                    aN0 = fmaf(hv, wE[k], aN0);
                    aN1 = fmaf(hv, wF[k], aN1);
                    if (SEL) if (u == 0) dot = fmaf(hv, Ws[H_ + k] - Ws[k], dot);
                }
            } else {
                if (u == 0) {
                    #pragma unroll 4
                    for (int kk = 0; kk < 128; ++kk) {
                        const int k = k0 + kk;
                        dot = fmaf(hs[kk * 64 + b], Ws[H_ + k] - Ws[k], dot);
                    }
                }
            }
        }

        if (!last) {
            float ir0, iz0, in0, ir1, iz1, in1;
            if (SEL) {
                const float* gb = giF + ((size_t)b * T_ + t) * G_;
                ir0 = gb[i0];        ir1 = gb[i0+1];
                iz0 = gb[H_+i0];     iz1 = gb[H_+i0+1];
                in0 = gb[2*H_+i0];   in1 = gb[2*H_+i0+1];
            } else {
                const __hip_bfloat16* gb = giB + ((size_t)b * T_ + t) * G_;
                ir0 = __bfloat162float(gb[i0]);        ir1 = __bfloat162float(gb[i0+1]);
                iz0 = __bfloat162float(gb[H_+i0]);     iz1 = __bfloat162float(gb[H_+i0+1]);
                in0 = __bfloat162float(gb[2*H_+i0]);   in1 = __bfloat162float(gb[2*H_+i0+1]);
            }
            const float hp0 = hcur[(size_t)(i0    ) * 64 + b];
            const float hp1 = hcur[(size_t)(i0 + 1) * 64 + b];
            float r0 = 1.f / (1.f + expf(-(ir0 + aR0)));
            float r1 = 1.f / (1.f + expf(-(ir1 + aR1)));
            float z0 = 1.f / (1.f + expf(-(iz0 + aZ0)));
            float z1 = 1.f / (1.f + expf(-(iz1 + aZ1)));
            float nn0 = tanhf(in0 + r0 * aN0);
            float nn1 = tanhf(in1 + r1 * aN1);
            float hn0 = (1.f - z0) * nn0 + z0 * hp0;
            float hn1 = (1.f - z1) * nn1 + z1 * hp1;
            if (!SEL) {
                const bool v = t < ns;
                if (v) {
                    float* op = outp + ((size_t)b * T_ + t) * H_;
                    op[i0] = hn0; op[i0 + 1] = hn1;
                } else { hn0 = hp0; hn1 = hp1; }
            }
            hnxt[(size_t)(i0    ) * 64 + b] = hn0;
            hnxt[(size_t)(i0 + 1) * 64 + b] = hn1;
        }

        if (SEL && t >= 1 && u == 0 && blockIdx.x == 0)
            selp[b * T_ + (t - 1)] = ((dot + db) > 0.f) ? 1 : 0;

        if (t + 1 < TOTAL) {                // grid barrier
            ++gen;
            __syncthreads();
            if (tid == 0) {
                __threadfence();            // device-scope release of h writes
                atomicAdd(cnt, 1);
                while (__hip_atomic_load(cnt, __ATOMIC_ACQUIRE,
                                         __HIP_MEMORY_SCOPE_AGENT) < 64 * gen)
                    __builtin_amdgcn_s_sleep(1);
            }
            __syncthreads();
        }
    }
}

// =====================================================================
// Per-batch selection post-processing: forcing rules, nsel, stable
// partition order, maxNsel. 1 block x 64 threads (thread = batch).
// =====================================================================
__global__ void build_order_k(const int* __restrict__ mask, const int* __restrict__ sel,
                              int* __restrict__ order, int* __restrict__ nsel,
                              int* __restrict__ maxn)
{
    const int b = threadIdx.x;
    int lens = 0;
    for (int t = 0; t < T_; ++t) lens += (mask[b * T_ + t] != 0);
    int cnt = 0;
    for (int t = 0; t < T_; ++t) {
        int s = sel[b * T_ + t];
        if (t == 0) s = 1;
        if (t == lens - 1) s = 1;
        if (t >= lens) s = 0;
        if (s) order[b * T_ + (cnt++)] = t;
    }
    nsel[b] = cnt;
    int c2 = cnt;
    for (int t = 0; t < T_; ++t) {
        int s = sel[b * T_ + t];
        if (t == 0) s = 1;
        if (t == lens - 1) s = 1;
        if (t >= lens) s = 0;
        if (!s) order[b * T_ + (c2++)] = t;
    }
    __shared__ int red[64];
    red[b] = cnt;
    __syncthreads();
    if (b == 0) {
        int m = 0;
        for (int q = 0; q < 64; ++q) m = max(m, red[q]);
        *maxn = m;
    }
}

// =====================================================================
// Final linear: out[b] = pooled[b] . Wo + bo
// =====================================================================
__global__ void final_k(const unsigned int* __restrict__ pool,
                        const float* __restrict__ Wo, const float* __restrict__ bo,
                        float* __restrict__ out)
{
    const int b = threadIdx.x;
    float s = bo[0];
    for (int f = 0; f < 3 * NF_; ++f)
        s = fmaf(__uint_as_float(pool[b * (3*NF_) + f]), Wo[f], s);
    out[b] = s;
}

// =====================================================================
extern "C" void kernel_launch(void* const* d_in, const int* in_sizes, int n_in,
                              void* d_out, int out_size, void* d_ws, size_t ws_size,
                              hipStream_t stream)
{
    (void)in_sizes; (void)n_in; (void)out_size;
    const float* emb   = (const float*)d_in[0];
    const int*   mask  = (const int*)d_in[1];
    const float* Wih_c = (const float*)d_in[2];
    const float* Whh_c = (const float*)d_in[3];
    const float* bih_c = (const float*)d_in[4];
    const float* bhh_c = (const float*)d_in[5];
    const float* Ws    = (const float*)d_in[6];
    const float* bs    = (const float*)d_in[7];
    const float* Wih0  = (const float*)d_in[8];
    const float* Whh0  = (const float*)d_in[9];
    const float* bih0  = (const float*)d_in[10];
    const float* bhh0  = (const float*)d_in[11];
    const float* Wih1  = (const float*)d_in[12];
    const float* Whh1  = (const float*)d_in[13];
    const float* bih1  = (const float*)d_in[14];
    const float* bhh1  = (const float*)d_in[15];
    const float* Wc3   = (const float*)d_in[16];
    const float* bc3   = (const float*)d_in[17];
    const float* Wc4   = (const float*)d_in[18];
    const float* bc4   = (const float*)d_in[19];
    const float* Wc5   = (const float*)d_in[20];
    const float* bc5   = (const float*)d_in[21];
    const float* Wo    = (const float*)d_in[22];
    const float* bo    = (const float*)d_in[23];

    if (ws_size < WS_NEED) return;   // workspace too small: fail loudly (poisoned out)
    char* ws = (char*)d_ws;
    float*          giC    = (float*)(ws + OFF_GI);
    __hip_bfloat16* giB    = (__hip_bfloat16*)(ws + OFF_GI);
    float*          outbuf = (float*)(ws + OFF_OUT);
    float*          h0     = (float*)(ws + OFF_H0);
    float*          h1     = (float*)(ws + OFF_H1);
    int*            sel    = (int*)(ws + OFF_SEL);
    int*            order  = (int*)(ws + OFF_ORD);
    int*            nsel   = (int*)(ws + OFF_NSEL);
    int*            maxn   = (int*)(ws + OFF_MAXN);
    int*            cnt    = (int*)(ws + OFF_CNT);
    unsigned int*   pool   = (unsigned int*)(ws + OFF_POOL);

    // 1. gi_c = emb @ Wih_c^T + bih_c  (fp32 — argmax precision)
    gemm_k<0,0><<<dim3(512, 24), 256, 0, stream>>>(emb, Wih_c, bih_c, giC, nullptr, nullptr,
                                                   G_, E_, E_, 0, 0, nullptr, nullptr, 0);
    // 2. selector recurrence -> sel
    hipMemsetAsync(cnt, 0, 4, stream);
    hipMemsetAsync(h0, 0, (size_t)B_ * H_ * 4, stream);
    rec_k<true><<<64, 256, 0, stream>>>(giC, nullptr, Whh_c, bhh_c, Ws, bs, nullptr, nullptr,
                                        h0, h1, nullptr, sel, cnt);
    // 3. forcing + stable partition
    build_order_k<<<1, 64, 0, stream>>>(mask, sel, order, nsel, maxn);
    // 4. gi0 = new_emb @ Wih0^T + bih0 (gathered rows, bf16 out)
    gemm_k<1,1><<<dim3(512, 24), 256, 0, stream>>>(emb, Wih0, bih0, nullptr, giB, nullptr,
                                                   G_, E_, E_, T_, 8, order, nsel, 0);
    // 5. layer0 recurrence -> out0
    hipMemsetAsync(cnt, 0, 4, stream);
    hipMemsetAsync(h0, 0, (size_t)B_ * H_ * 4, stream);
    hipMemsetAsync(outbuf, 0, (size_t)B_ * T_ * H_ * 4, stream);
    rec_k<false><<<64, 256, 0, stream>>>(nullptr, giB, Whh0, bhh0, nullptr, nullptr, nsel, maxn,
                                         h0, h1, outbuf, nullptr, cnt);
    // 6. gi1 = out0 @ Wih1^T + bih1 (bf16 out; reads out0 region, writes gi region)
    gemm_k<0,1><<<dim3(512, 24), 256, 0, stream>>>(outbuf, Wih1, bih1, nullptr, giB, nullptr,
                                                   G_, H_, H_, 0, 0, nullptr, nullptr, 0);
    // 7. layer1 recurrence -> out1 (overwrites out0)
    hipMemsetAsync(cnt, 0, 4, stream);
    hipMemsetAsync(h0, 0, (size_t)B_ * H_ * 4, stream);
    hipMemsetAsync(outbuf, 0, (size_t)B_ * T_ * H_ * 4, stream);
    rec_k<false><<<64, 256, 0, stream>>>(nullptr, giB, Whh1, bhh1, nullptr, nullptr, nsel, maxn,
                                         h0, h1, outbuf, nullptr, cnt);
    // 8. convs (sliding-window GEMM) + relu + time-max pooling
    hipMemsetAsync(pool, 0, (size_t)B_ * 3 * NF_ * 4, stream);
    gemm_k<2,2><<<dim3(512, 4), 256, 0, stream>>>(outbuf, Wc3, bc3, nullptr, nullptr, pool,
                                                  NF_, 3 * H_, H_, 510, 8, nullptr, nullptr, 0);
    gemm_k<2,2><<<dim3(512, 4), 256, 0, stream>>>(outbuf, Wc4, bc4, nullptr, nullptr, pool,
                                                  NF_, 4 * H_, H_, 509, 8, nullptr, nullptr, 256);
    gemm_k<2,2><<<dim3(512, 4), 256, 0, stream>>>(outbuf, Wc5, bc5, nullptr, nullptr, pool,
                                                  NF_, 5 * H_, H_, 508, 8, nullptr, nullptr, 512);
    // 9. final linear -> d_out (64 f32)
    final_k<<<1, 64, 0, stream>>>(pool, Wo, bo, (float*)d_out);
}

// Round 2
// 46685.699 us; speedup vs baseline: 1.4132x; 1.4132x over previous
//
#include <hip/hip_runtime.h>
#include <hip/hip_bf16.h>
#include <cstddef>

// ---------------- problem constants ----------------
constexpr int B_ = 64, T_ = 512, E_ = 768, H_ = 512, G_ = 1536, NF_ = 256;

// ---------------- workspace layout (bytes) ----------------
constexpr size_t SZ_GIC   = (size_t)B_ * T_ * G_ * 4;       // 201326592
constexpr size_t OFF_GI   = 0;
constexpr size_t OFF_OUT  = (size_t)B_ * T_ * G_ * 2;       // out f32 after bf16 gi
constexpr size_t OFF_MISC = SZ_GIC;
constexpr size_t OFF_H0   = OFF_MISC;
constexpr size_t OFF_H1   = OFF_H0 + (size_t)B_ * H_ * 4;
constexpr size_t OFF_SEL  = OFF_H1 + (size_t)B_ * H_ * 4;
constexpr size_t OFF_ORD  = OFF_SEL + (size_t)B_ * T_ * 4;
constexpr size_t OFF_NSEL = OFF_ORD + (size_t)B_ * T_ * 4;
constexpr size_t OFF_MAXN = OFF_NSEL + 256;
constexpr size_t OFF_CNT  = OFF_MAXN + 256;
constexpr size_t OFF_POOL = OFF_CNT + 256;
constexpr size_t WS_NEED  = OFF_POOL + (size_t)B_ * 3 * NF_ * 4;

// =====================================================================
// Tiled fp32 GEMM (unchanged from round 1 — attacked next round).
// =====================================================================
template<int AMODE, int OMODE>
__global__ __launch_bounds__(256) void gemm_k(
    const float* __restrict__ A, const float* __restrict__ W,
    const float* __restrict__ bias,
    float* __restrict__ Cf, __hip_bfloat16* __restrict__ Cb,
    unsigned int* __restrict__ pool,
    int N, int K, int ldA, int rowsPerB, int tilesPerB,
    const int* __restrict__ order, const int* __restrict__ nsel, int poolOff)
{
    __shared__ float As[64 * 20];
    __shared__ float Bs[64 * 20];
    __shared__ const float* rowp[64];
    __shared__ float rowsc[64];

    const int tid = threadIdx.x;
    const int tx = tid & 15, ty = tid >> 4;
    const int bx = blockIdx.x;
    const int n0 = blockIdx.y * 64;

    int tileb = 0, tilet0 = 0;
    if (AMODE != 0) { tileb = bx / tilesPerB; tilet0 = (bx % tilesPerB) * 64; }

    if (tid < 64) {
        const float* p = nullptr; float sc = 1.f;
        if (AMODE == 0) {
            p = A + ((size_t)bx * 64 + tid) * (size_t)ldA;
        } else if (AMODE == 1) {
            int t = tilet0 + tid;
            int src = order[tileb * T_ + t];
            p = A + ((size_t)tileb * T_ + src) * (size_t)ldA;
            sc = (t < nsel[tileb]) ? 1.f : 0.f;
        } else {
            int t = tilet0 + tid;
            if (t < rowsPerB) p = A + ((size_t)tileb * T_ + t) * (size_t)H_;
        }
        rowp[tid] = p; rowsc[tid] = sc;
    }
    __syncthreads();

    float acc[4][4] = {};
    const int rl = tid >> 2, kl = (tid & 3) * 4;
    const float* __restrict__ ap = rowp[rl];
    const float  asc = rowsc[rl];
    const float* __restrict__ wrow = W + (size_t)(n0 + rl) * (size_t)K + kl;

    for (int k0 = 0; k0 < K; k0 += 16) {
        float4 av = make_float4(0.f, 0.f, 0.f, 0.f);
        if (ap) av = *(const float4*)(ap + k0 + kl);
        float4 wv = *(const float4*)(wrow + k0);
        __syncthreads();
        As[rl*20+kl+0] = av.x * asc; As[rl*20+kl+1] = av.y * asc;
        As[rl*20+kl+2] = av.z * asc; As[rl*20+kl+3] = av.w * asc;
        Bs[rl*20+kl+0] = wv.x; Bs[rl*20+kl+1] = wv.y;
        Bs[rl*20+kl+2] = wv.z; Bs[rl*20+kl+3] = wv.w;
        __syncthreads();
        #pragma unroll
        for (int kk = 0; kk < 16; ++kk) {
            float a0 = As[(ty*4+0)*20+kk], a1 = As[(ty*4+1)*20+kk];
            float a2 = As[(ty*4+2)*20+kk], a3 = As[(ty*4+3)*20+kk];
            float w0 = Bs[(tx*4+0)*20+kk], w1 = Bs[(tx*4+1)*20+kk];
            float w2 = Bs[(tx*4+2)*20+kk], w3 = Bs[(tx*4+3)*20+kk];
            acc[0][0]=fmaf(a0,w0,acc[0][0]); acc[0][1]=fmaf(a0,w1,acc[0][1]);
            acc[0][2]=fmaf(a0,w2,acc[0][2]); acc[0][3]=fmaf(a0,w3,acc[0][3]);
            acc[1][0]=fmaf(a1,w0,acc[1][0]); acc[1][1]=fmaf(a1,w1,acc[1][1]);
            acc[1][2]=fmaf(a1,w2,acc[1][2]); acc[1][3]=fmaf(a1,w3,acc[1][3]);
            acc[2][0]=fmaf(a2,w0,acc[2][0]); acc[2][1]=fmaf(a2,w1,acc[2][1]);
            acc[2][2]=fmaf(a2,w2,acc[2][2]); acc[2][3]=fmaf(a2,w3,acc[2][3]);
            acc[3][0]=fmaf(a3,w0,acc[3][0]); acc[3][1]=fmaf(a3,w1,acc[3][1]);
            acc[3][2]=fmaf(a3,w2,acc[3][2]); acc[3][3]=fmaf(a3,w3,acc[3][3]);
        }
    }

    if (OMODE == 0 || OMODE == 1) {
        #pragma unroll
        for (int i = 0; i < 4; ++i) {
            int m;
            if (AMODE == 0) m = bx * 64 + ty*4 + i;
            else            m = tileb * T_ + tilet0 + ty*4 + i;
            size_t co = (size_t)m * (size_t)N + n0 + tx*4;
            #pragma unroll
            for (int j = 0; j < 4; ++j) {
                float v = acc[i][j] + bias[n0 + tx*4 + j];
                if (OMODE == 0) Cf[co + j] = v;
                else            Cb[co + j] = __float2bfloat16(v);
            }
        }
    } else {
        float mx[4] = {0.f, 0.f, 0.f, 0.f};
        #pragma unroll
        for (int i = 0; i < 4; ++i) {
            int t = tilet0 + ty*4 + i;
            bool v = t < rowsPerB;
            #pragma unroll
            for (int j = 0; j < 4; ++j) {
                float val = fmaxf(acc[i][j] + bias[n0 + tx*4 + j], 0.f);
                if (v) mx[j] = fmaxf(mx[j], val);
            }
        }
        __syncthreads();
        #pragma unroll
        for (int j = 0; j < 4; ++j) As[(tx*4+j)*17 + ty] = mx[j];
        __syncthreads();
        if (tid < 64) {
            float m = 0.f;
            #pragma unroll
            for (int q = 0; q < 16; ++q) m = fmaxf(m, As[tid*17 + q]);
            atomicMax(&pool[(size_t)tileb * (3*NF_) + poolOff + n0 + tid],
                      __float_as_uint(m));
        }
    }
}

// =====================================================================
// GRU recurrence v2: fence-free coherent h exchange.
// 64 WGs x 512 threads (8 waves); wave w owns unit i = bx*8+w, lane = batch.
// h ping-pong in global [k][b] layout, accessed ONLY via relaxed agent-scope
// atomics (coherent, no cache-maintenance => weights stay L1/L2-hot).
// Barrier: per-wave vmcnt drain + __syncthreads, relaxed atomicAdd, relaxed
// spin (in-order wave issue makes post-spin coherent loads see published h).
// SEL: WG0 computes selector logits k-split across its 8 waves from the
// staged h(t) => sel[t-1]; one extra stage-only iteration for sel[T-1].
// =====================================================================
template<bool SEL>
__global__ __launch_bounds__(512) void rec_k(
    const float* __restrict__ giF, const __hip_bfloat16* __restrict__ giB,
    const float* __restrict__ Whh, const float* __restrict__ bhh,
    const float* __restrict__ Ws, const float* __restrict__ bs,
    const int* __restrict__ nselp, const int* __restrict__ maxnp,
    float* __restrict__ h0, float* __restrict__ h1,
    float* __restrict__ outp, int* __restrict__ selp,
    int* __restrict__ cnt)
{
    __shared__ float hs[H_ * 64];     // 128KB: full h, [k][b]
    __shared__ float sred[8 * 64];    // SEL partial dots (WG0)
    __shared__ float dW[H_];          // SEL: Ws[1]-Ws[0]

    const int tid = threadIdx.x;
    const int b = tid & 63;
    const int w = __builtin_amdgcn_readfirstlane(tid >> 6);
    const int i = blockIdx.x * 8 + w;

    const float* __restrict__ wR = Whh + (size_t)i * H_;
    const float* __restrict__ wZ = Whh + (size_t)(H_ + i) * H_;
    const float* __restrict__ wN = Whh + (size_t)(2 * H_ + i) * H_;
    const float bhR = bhh[i], bhZ = bhh[H_ + i], bhN = bhh[2 * H_ + i];

    const int ns = SEL ? 0 : nselp[b];
    const float db = SEL ? (bs[1] - bs[0]) : 0.f;
    const int TOTAL = SEL ? (T_ + 1) : *maxnp;

    if (SEL && blockIdx.x == 0)
        dW[tid] = Ws[H_ + tid] - Ws[tid];   // 512 threads == H_

    int gen = 0;
    for (int t = 0; t < TOTAL; ++t) {
        const float* hcur = (t & 1) ? h1 : h0;
        float* hnxt = (t & 1) ? h0 : h1;

        // ---- stage full h(t) into LDS (coherent, coalesced) ----
        #pragma unroll 8
        for (int j = 0; j < 64; ++j) {
            const int idx = j * 512 + tid;
            hs[idx] = __hip_atomic_load(hcur + idx, __ATOMIC_RELAXED,
                                        __HIP_MEMORY_SCOPE_AGENT);
        }
        __syncthreads();

        // ---- selector logits (WG0 only): sel[t-1] from h(t) ----
        if (SEL && blockIdx.x == 0 && t >= 1) {
            float part = 0.f;
            const int kb = w * 64;
            #pragma unroll 8
            for (int j = 0; j < 64; ++j)
                part = fmaf(hs[(kb + j) * 64 + b], dW[kb + j], part);
            sred[w * 64 + b] = part;
            __syncthreads();
            if (tid < 64) {
                float dot = db;
                #pragma unroll
                for (int q = 0; q < 8; ++q) dot += sred[q * 64 + tid];
                selp[tid * T_ + (t - 1)] = (dot > 0.f) ? 1 : 0;
            }
        }

        // ---- gate compute + h(t+1) publish ----
        if (!(SEL && t == T_)) {
            float aR = bhR, aZ = bhZ, aN = bhN;
            #pragma unroll 8
            for (int k = 0; k < H_; ++k) {
                const float hv = hs[k * 64 + b];
                aR = fmaf(hv, wR[k], aR);
                aZ = fmaf(hv, wZ[k], aZ);
                aN = fmaf(hv, wN[k], aN);
            }
            float ir, iz, in_;
            if (SEL) {
                const float* gb = giF + ((size_t)b * T_ + t) * G_;
                ir = gb[i]; iz = gb[H_ + i]; in_ = gb[2 * H_ + i];
            } else {
                const __hip_bfloat16* gb = giB + ((size_t)b * T_ + t) * G_;
                ir  = __bfloat162float(gb[i]);
                iz  = __bfloat162float(gb[H_ + i]);
                in_ = __bfloat162float(gb[2 * H_ + i]);
            }
            const float hp = hs[i * 64 + b];
            const float r = 1.f / (1.f + expf(-(ir + aR)));
            const float z = 1.f / (1.f + expf(-(iz + aZ)));
            const float n = tanhf(in_ + r * aN);
            float hn = (1.f - z) * n + z * hp;
            if (!SEL) {
                if (t < ns) outp[((size_t)b * T_ + t) * H_ + i] = hn;
                else hn = hp;
            }
            __hip_atomic_store(hnxt + (size_t)i * 64 + b, hn, __ATOMIC_RELAXED,
                               __HIP_MEMORY_SCOPE_AGENT);
        }

        // ---- fence-free grid barrier ----
        if (t + 1 < TOTAL) {
            ++gen;
            asm volatile("s_waitcnt vmcnt(0)" ::: "memory");  // h stores complete
            __syncthreads();                                   // all waves drained
            if (tid == 0) {
                __hip_atomic_fetch_add(cnt, 1, __ATOMIC_RELAXED,
                                       __HIP_MEMORY_SCOPE_AGENT);
                while (__hip_atomic_load(cnt, __ATOMIC_RELAXED,
                                         __HIP_MEMORY_SCOPE_AGENT) < 64 * gen)
                    __builtin_amdgcn_s_sleep(2);
            }
            __syncthreads();
        }
    }
}

// =====================================================================
// Per-batch selection post-processing (unchanged).
// =====================================================================
__global__ void build_order_k(const int* __restrict__ mask, const int* __restrict__ sel,
                              int* __restrict__ order, int* __restrict__ nsel,
                              int* __restrict__ maxn)
{
    const int b = threadIdx.x;
    int lens = 0;
    for (int t = 0; t < T_; ++t) lens += (mask[b * T_ + t] != 0);
    int cnt = 0;
    for (int t = 0; t < T_; ++t) {
        int s = sel[b * T_ + t];
        if (t == 0) s = 1;
        if (t == lens - 1) s = 1;
        if (t >= lens) s = 0;
        if (s) order[b * T_ + (cnt++)] = t;
    }
    nsel[b] = cnt;
    int c2 = cnt;
    for (int t = 0; t < T_; ++t) {
        int s = sel[b * T_ + t];
        if (t == 0) s = 1;
        if (t == lens - 1) s = 1;
        if (t >= lens) s = 0;
        if (!s) order[b * T_ + (c2++)] = t;
    }
    __shared__ int red[64];
    red[b] = cnt;
    __syncthreads();
    if (b == 0) {
        int m = 0;
        for (int q = 0; q < 64; ++q) m = max(m, red[q]);
        *maxn = m;
    }
}

// =====================================================================
// Final linear (unchanged).
// =====================================================================
__global__ void final_k(const unsigned int* __restrict__ pool,
                        const float* __restrict__ Wo, const float* __restrict__ bo,
                        float* __restrict__ out)
{
    const int b = threadIdx.x;
    float s = bo[0];
    for (int f = 0; f < 3 * NF_; ++f)
        s = fmaf(__uint_as_float(pool[b * (3*NF_) + f]), Wo[f], s);
    out[b] = s;
}

// =====================================================================
extern "C" void kernel_launch(void* const* d_in, const int* in_sizes, int n_in,
                              void* d_out, int out_size, void* d_ws, size_t ws_size,
                              hipStream_t stream)
{
    (void)in_sizes; (void)n_in; (void)out_size;
    const float* emb   = (const float*)d_in[0];
    const int*   mask  = (const int*)d_in[1];
    const float* Wih_c = (const float*)d_in[2];
    const float* Whh_c = (const float*)d_in[3];
    const float* bih_c = (const float*)d_in[4];
    const float* bhh_c = (const float*)d_in[5];
    const float* Ws    = (const float*)d_in[6];
    const float* bs    = (const float*)d_in[7];
    const float* Wih0  = (const float*)d_in[8];
    const float* Whh0  = (const float*)d_in[9];
    const float* bih0  = (const float*)d_in[10];
    const float* bhh0  = (const float*)d_in[11];
    const float* Wih1  = (const float*)d_in[12];
    const float* Whh1  = (const float*)d_in[13];
    const float* bih1  = (const float*)d_in[14];
    const float* bhh1  = (const float*)d_in[15];
    const float* Wc3   = (const float*)d_in[16];
    const float* bc3   = (const float*)d_in[17];
    const float* Wc4   = (const float*)d_in[18];
    const float* bc4   = (const float*)d_in[19];
    const float* Wc5   = (const float*)d_in[20];
    const float* bc5   = (const float*)d_in[21];
    const float* Wo    = (const float*)d_in[22];
    const float* bo    = (const float*)d_in[23];

    if (ws_size < WS_NEED) return;
    char* ws = (char*)d_ws;
    float*          giC    = (float*)(ws + OFF_GI);
    __hip_bfloat16* giB    = (__hip_bfloat16*)(ws + OFF_GI);
    float*          outbuf = (float*)(ws + OFF_OUT);
    float*          h0     = (float*)(ws + OFF_H0);
    float*          h1     = (float*)(ws + OFF_H1);
    int*            sel    = (int*)(ws + OFF_SEL);
    int*            order  = (int*)(ws + OFF_ORD);
    int*            nsel   = (int*)(ws + OFF_NSEL);
    int*            maxn   = (int*)(ws + OFF_MAXN);
    int*            cnt    = (int*)(ws + OFF_CNT);
    unsigned int*   pool   = (unsigned int*)(ws + OFF_POOL);

    // 1. gi_c = emb @ Wih_c^T + bih_c  (fp32 — argmax precision)
    gemm_k<0,0><<<dim3(512, 24), 256, 0, stream>>>(emb, Wih_c, bih_c, giC, nullptr, nullptr,
                                                   G_, E_, E_, 0, 0, nullptr, nullptr, 0);
    // 2. selector recurrence -> sel
    hipMemsetAsync(cnt, 0, 4, stream);
    hipMemsetAsync(h0, 0, (size_t)B_ * H_ * 4, stream);
    rec_k<true><<<64, 512, 0, stream>>>(giC, nullptr, Whh_c, bhh_c, Ws, bs, nullptr, nullptr,
                                        h0, h1, nullptr, sel, cnt);
    // 3. forcing + stable partition
    build_order_k<<<1, 64, 0, stream>>>(mask, sel, order, nsel, maxn);
    // 4. gi0 = new_emb @ Wih0^T + bih0 (gathered rows, bf16 out)
    gemm_k<1,1><<<dim3(512, 24), 256, 0, stream>>>(emb, Wih0, bih0, nullptr, giB, nullptr,
                                                   G_, E_, E_, T_, 8, order, nsel, 0);
    // 5. layer0 recurrence -> out0
    hipMemsetAsync(cnt, 0, 4, stream);
    hipMemsetAsync(h0, 0, (size_t)B_ * H_ * 4, stream);
    hipMemsetAsync(outbuf, 0, (size_t)B_ * T_ * H_ * 4, stream);
    rec_k<false><<<64, 512, 0, stream>>>(nullptr, giB, Whh0, bhh0, nullptr, nullptr, nsel, maxn,
                                         h0, h1, outbuf, nullptr, cnt);
    // 6. gi1 = out0 @ Wih1^T + bih1 (bf16 out)
    gemm_k<0,1><<<dim3(512, 24), 256, 0, stream>>>(outbuf, Wih1, bih1, nullptr, giB, nullptr,
                                                   G_, H_, H_, 0, 0, nullptr, nullptr, 0);
    // 7. layer1 recurrence -> out1 (overwrites out0)
    hipMemsetAsync(cnt, 0, 4, stream);
    hipMemsetAsync(h0, 0, (size_t)B_ * H_ * 4, stream);
    hipMemsetAsync(outbuf, 0, (size_t)B_ * T_ * H_ * 4, stream);
    rec_k<false><<<64, 512, 0, stream>>>(nullptr, giB, Whh1, bhh1, nullptr, nullptr, nsel, maxn,
                                         h0, h1, outbuf, nullptr, cnt);
    // 8. convs (sliding-window GEMM) + relu + time-max pooling
    hipMemsetAsync(pool, 0, (size_t)B_ * 3 * NF_ * 4, stream);
    gemm_k<2,2><<<dim3(512, 4), 256, 0, stream>>>(outbuf, Wc3, bc3, nullptr, nullptr, pool,
                                                  NF_, 3 * H_, H_, 510, 8, nullptr, nullptr, 0);
    gemm_k<2,2><<<dim3(512, 4), 256, 0, stream>>>(outbuf, Wc4, bc4, nullptr, nullptr, pool,
                                                  NF_, 4 * H_, H_, 509, 8, nullptr, nullptr, 256);
    gemm_k<2,2><<<dim3(512, 4), 256, 0, stream>>>(outbuf, Wc5, bc5, nullptr, nullptr, pool,
                                                  NF_, 5 * H_, H_, 508, 8, nullptr, nullptr, 512);
    // 9. final linear -> d_out (64 f32)
    final_k<<<1, 64, 0, stream>>>(pool, Wo, bo, (float*)d_out);
}

// Round 3
// 31401.111 us; speedup vs baseline: 2.1011x; 1.4868x over previous
//
#include <hip/hip_runtime.h>
#include <hip/hip_bf16.h>
#include <cstddef>

// ---------------- problem constants ----------------
constexpr int B_ = 64, T_ = 512, E_ = 768, H_ = 512, G_ = 1536, NF_ = 256;

// ---------------- workspace layout (bytes) ----------------
constexpr size_t SZ_GIC   = (size_t)B_ * T_ * G_ * 4;       // 201326592
constexpr size_t OFF_GI   = 0;
constexpr size_t OFF_OUT  = (size_t)B_ * T_ * G_ * 2;       // out f32 after bf16 gi
constexpr size_t OFF_MISC = SZ_GIC;
constexpr size_t OFF_H0   = OFF_MISC;
constexpr size_t OFF_H1   = OFF_H0 + (size_t)B_ * H_ * 4;
constexpr size_t OFF_SEL  = OFF_H1 + (size_t)B_ * H_ * 4;
constexpr size_t OFF_ORD  = OFF_SEL + (size_t)B_ * T_ * 4;
constexpr size_t OFF_NSEL = OFF_ORD + (size_t)B_ * T_ * 4;
constexpr size_t OFF_MAXN = OFF_NSEL + 256;
constexpr size_t OFF_FLG  = OFF_MAXN + 256;                 // 64 ints
constexpr size_t OFF_POOL = OFF_FLG + 256;
constexpr size_t WS_NEED  = OFF_POOL + (size_t)B_ * 3 * NF_ * 4;

// coherent (IF$-level, L1/L2-bypass) access helpers
#define CLOAD4(dst, ptr) \
    asm volatile("global_load_dwordx4 %0, %1, off sc0 sc1" : "=v"(dst) : "v"(ptr))
#define CWAIT() do { \
    asm volatile("s_waitcnt vmcnt(0)" ::: "memory"); \
    __builtin_amdgcn_sched_barrier(0); } while (0)

// =====================================================================
// Tiled fp32 GEMM (unchanged — MFMA conversion next round).
// =====================================================================
template<int AMODE, int OMODE>
__global__ __launch_bounds__(256) void gemm_k(
    const float* __restrict__ A, const float* __restrict__ W,
    const float* __restrict__ bias,
    float* __restrict__ Cf, __hip_bfloat16* __restrict__ Cb,
    unsigned int* __restrict__ pool,
    int N, int K, int ldA, int rowsPerB, int tilesPerB,
    const int* __restrict__ order, const int* __restrict__ nsel, int poolOff)
{
    __shared__ float As[64 * 20];
    __shared__ float Bs[64 * 20];
    __shared__ const float* rowp[64];
    __shared__ float rowsc[64];

    const int tid = threadIdx.x;
    const int tx = tid & 15, ty = tid >> 4;
    const int bx = blockIdx.x;
    const int n0 = blockIdx.y * 64;

    int tileb = 0, tilet0 = 0;
    if (AMODE != 0) { tileb = bx / tilesPerB; tilet0 = (bx % tilesPerB) * 64; }

    if (tid < 64) {
        const float* p = nullptr; float sc = 1.f;
        if (AMODE == 0) {
            p = A + ((size_t)bx * 64 + tid) * (size_t)ldA;
        } else if (AMODE == 1) {
            int t = tilet0 + tid;
            int src = order[tileb * T_ + t];
            p = A + ((size_t)tileb * T_ + src) * (size_t)ldA;
            sc = (t < nsel[tileb]) ? 1.f : 0.f;
        } else {
            int t = tilet0 + tid;
            if (t < rowsPerB) p = A + ((size_t)tileb * T_ + t) * (size_t)H_;
        }
        rowp[tid] = p; rowsc[tid] = sc;
    }
    __syncthreads();

    float acc[4][4] = {};
    const int rl = tid >> 2, kl = (tid & 3) * 4;
    const float* __restrict__ ap = rowp[rl];
    const float  asc = rowsc[rl];
    const float* __restrict__ wrow = W + (size_t)(n0 + rl) * (size_t)K + kl;

    for (int k0 = 0; k0 < K; k0 += 16) {
        float4 av = make_float4(0.f, 0.f, 0.f, 0.f);
        if (ap) av = *(const float4*)(ap + k0 + kl);
        float4 wv = *(const float4*)(wrow + k0);
        __syncthreads();
        As[rl*20+kl+0] = av.x * asc; As[rl*20+kl+1] = av.y * asc;
        As[rl*20+kl+2] = av.z * asc; As[rl*20+kl+3] = av.w * asc;
        Bs[rl*20+kl+0] = wv.x; Bs[rl*20+kl+1] = wv.y;
        Bs[rl*20+kl+2] = wv.z; Bs[rl*20+kl+3] = wv.w;
        __syncthreads();
        #pragma unroll
        for (int kk = 0; kk < 16; ++kk) {
            float a0 = As[(ty*4+0)*20+kk], a1 = As[(ty*4+1)*20+kk];
            float a2 = As[(ty*4+2)*20+kk], a3 = As[(ty*4+3)*20+kk];
            float w0 = Bs[(tx*4+0)*20+kk], w1 = Bs[(tx*4+1)*20+kk];
            float w2 = Bs[(tx*4+2)*20+kk], w3 = Bs[(tx*4+3)*20+kk];
            acc[0][0]=fmaf(a0,w0,acc[0][0]); acc[0][1]=fmaf(a0,w1,acc[0][1]);
            acc[0][2]=fmaf(a0,w2,acc[0][2]); acc[0][3]=fmaf(a0,w3,acc[0][3]);
            acc[1][0]=fmaf(a1,w0,acc[1][0]); acc[1][1]=fmaf(a1,w1,acc[1][1]);
            acc[1][2]=fmaf(a1,w2,acc[1][2]); acc[1][3]=fmaf(a1,w3,acc[1][3]);
            acc[2][0]=fmaf(a2,w0,acc[2][0]); acc[2][1]=fmaf(a2,w1,acc[2][1]);
            acc[2][2]=fmaf(a2,w2,acc[2][2]); acc[2][3]=fmaf(a2,w3,acc[2][3]);
            acc[3][0]=fmaf(a3,w0,acc[3][0]); acc[3][1]=fmaf(a3,w1,acc[3][1]);
            acc[3][2]=fmaf(a3,w2,acc[3][2]); acc[3][3]=fmaf(a3,w3,acc[3][3]);
        }
    }

    if (OMODE == 0 || OMODE == 1) {
        #pragma unroll
        for (int i = 0; i < 4; ++i) {
            int m;
            if (AMODE == 0) m = bx * 64 + ty*4 + i;
            else            m = tileb * T_ + tilet0 + ty*4 + i;
            size_t co = (size_t)m * (size_t)N + n0 + tx*4;
            #pragma unroll
            for (int j = 0; j < 4; ++j) {
                float v = acc[i][j] + bias[n0 + tx*4 + j];
                if (OMODE == 0) Cf[co + j] = v;
                else            Cb[co + j] = __float2bfloat16(v);
            }
        }
    } else {
        float mx[4] = {0.f, 0.f, 0.f, 0.f};
        #pragma unroll
        for (int i = 0; i < 4; ++i) {
            int t = tilet0 + ty*4 + i;
            bool v = t < rowsPerB;
            #pragma unroll
            for (int j = 0; j < 4; ++j) {
                float val = fmaxf(acc[i][j] + bias[n0 + tx*4 + j], 0.f);
                if (v) mx[j] = fmaxf(mx[j], val);
            }
        }
        __syncthreads();
        #pragma unroll
        for (int j = 0; j < 4; ++j) As[(tx*4+j)*17 + ty] = mx[j];
        __syncthreads();
        if (tid < 64) {
            float m = 0.f;
            #pragma unroll
            for (int q = 0; q < 16; ++q) m = fmaxf(m, As[tid*17 + q]);
            atomicMax(&pool[(size_t)tileb * (3*NF_) + poolOff + n0 + tid],
                      __float_as_uint(m));
        }
    }
}

// =====================================================================
// GRU recurrence v3: wide coherent staging + flag barrier + gi prefetch.
// 64 WGs x 512 threads; wave w owns unit i = bx*8+w, lane = batch b.
// h ping-pong in global [k][b], accessed via sc0/sc1 (IF$-coherent,
// L1/L2-bypass) wide loads / dword stores. Stage in two 64KB chunks:
// chunk1's loads fly while chunk0's matvec runs. gi(t+1) prefetched into
// registers during step t's epilogue (normal cached loads, off critical
// path). Barrier: vmcnt-drain + syncthreads + flag store; waiters poll
// all 64 flags with one 64-lane coherent load.
// =====================================================================
template<bool SEL>
__global__ __launch_bounds__(512) void rec_k(
    const float* __restrict__ giF, const __hip_bfloat16* __restrict__ giB,
    const float* __restrict__ Whh, const float* __restrict__ bhh,
    const float* __restrict__ Ws, const float* __restrict__ bs,
    const int* __restrict__ nselp, const int* __restrict__ maxnp,
    float* __restrict__ h0, float* __restrict__ h1,
    float* __restrict__ outp, int* __restrict__ selp,
    int* __restrict__ flags)
{
    __shared__ float hs[H_ * 64];     // 128KB: full h(t), [k][b]
    __shared__ float sred[8 * 64];    // SEL partial dots (WG0)
    __shared__ float dW[H_];          // SEL: Ws[1]-Ws[0]

    const int tid = threadIdx.x;
    const int b = tid & 63;
    const int w = __builtin_amdgcn_readfirstlane(tid >> 6);
    const int i = blockIdx.x * 8 + w;
    const int bx = blockIdx.x;

    const float* __restrict__ wR = Whh + (size_t)i * H_;
    const float* __restrict__ wZ = Whh + (size_t)(H_ + i) * H_;
    const float* __restrict__ wN = Whh + (size_t)(2 * H_ + i) * H_;
    const float bhR = bhh[i], bhZ = bhh[H_ + i], bhN = bhh[2 * H_ + i];

    const int ns = SEL ? 0 : nselp[b];
    const float db = SEL ? (bs[1] - bs[0]) : 0.f;
    const int TOTAL = SEL ? (T_ + 1) : *maxnp;
    const int GI_N  = SEL ? T_ : TOTAL;     // steps that consume gi

    if (SEL && bx == 0) dW[tid] = Ws[H_ + tid] - Ws[tid];

    // ---- gi prefetch registers (gi(t) loaded during step t-1) ----
    float pgR = 0.f, pgZ = 0.f, pgN = 0.f;
    {
        if (SEL) {
            const float* gb = giF + (size_t)b * T_ * G_;      // t = 0
            pgR = gb[i]; pgZ = gb[H_ + i]; pgN = gb[2 * H_ + i];
        } else {
            const __hip_bfloat16* gb = giB + (size_t)b * T_ * G_;
            pgR = __bfloat162float(gb[i]);
            pgZ = __bfloat162float(gb[H_ + i]);
            pgN = __bfloat162float(gb[2 * H_ + i]);
        }
    }

    for (int t = 0; t < TOTAL; ++t) {
        const float* hcur = (t & 1) ? h1 : h0;
        float* hnxt = (t & 1) ? h0 : h1;

        // ---- wait for all WGs to have published h(t) ----
        if (t > 0) {
            if (tid < 64) {
                int v;
                for (;;) {
                    asm volatile("global_load_dword %0, %1, off sc0 sc1\n\t"
                                 "s_waitcnt vmcnt(0)"
                                 : "=v"(v) : "v"(flags + tid) : "memory");
                    if (__all(v >= t)) break;
                    __builtin_amdgcn_s_sleep(1);
                }
            }
            __syncthreads();
        }

        // ---- stage chunk0 (k in [0,256), 64KB), coherent dwordx4 ----
        const float* hc = hcur + (size_t)tid * 4;
        float* hd = hs + tid * 4;
        float4 a0,a1,a2,a3,a4,a5,a6,a7;
        CLOAD4(a0, hc + 0*2048); CLOAD4(a1, hc + 1*2048);
        CLOAD4(a2, hc + 2*2048); CLOAD4(a3, hc + 3*2048);
        CLOAD4(a4, hc + 4*2048); CLOAD4(a5, hc + 5*2048);
        CLOAD4(a6, hc + 6*2048); CLOAD4(a7, hc + 7*2048);
        CWAIT();
        *(float4*)(hd + 0*2048) = a0; *(float4*)(hd + 1*2048) = a1;
        *(float4*)(hd + 2*2048) = a2; *(float4*)(hd + 3*2048) = a3;
        *(float4*)(hd + 4*2048) = a4; *(float4*)(hd + 5*2048) = a5;
        *(float4*)(hd + 6*2048) = a6; *(float4*)(hd + 7*2048) = a7;
        __syncthreads();

        // ---- issue chunk1 loads (k in [256,512)); fly during compute ----
        float4 c0,c1,c2,c3,c4,c5,c6,c7;
        CLOAD4(c0, hc +  8*2048); CLOAD4(c1, hc +  9*2048);
        CLOAD4(c2, hc + 10*2048); CLOAD4(c3, hc + 11*2048);
        CLOAD4(c4, hc + 12*2048); CLOAD4(c5, hc + 13*2048);
        CLOAD4(c6, hc + 14*2048); CLOAD4(c7, hc + 15*2048);

        // ---- matvec chunk0 ----
        float aR = bhR, aZ = bhZ, aN = bhN;
        #pragma unroll 8
        for (int k = 0; k < 256; ++k) {
            const float hv = hs[k * 64 + b];
            aR = fmaf(hv, wR[k], aR);
            aZ = fmaf(hv, wZ[k], aZ);
            aN = fmaf(hv, wN[k], aN);
        }

        // ---- land chunk1, matvec chunk1 ----
        CWAIT();
        *(float4*)(hd +  8*2048) = c0; *(float4*)(hd +  9*2048) = c1;
        *(float4*)(hd + 10*2048) = c2; *(float4*)(hd + 11*2048) = c3;
        *(float4*)(hd + 12*2048) = c4; *(float4*)(hd + 13*2048) = c5;
        *(float4*)(hd + 14*2048) = c6; *(float4*)(hd + 15*2048) = c7;
        __syncthreads();
        #pragma unroll 8
        for (int k = 256; k < 512; ++k) {
            const float hv = hs[k * 64 + b];
            aR = fmaf(hv, wR[k], aR);
            aZ = fmaf(hv, wZ[k], aZ);
            aN = fmaf(hv, wN[k], aN);
        }

        // ---- selector logits (WG0): sel[t-1] from staged h(t) ----
        if (SEL && bx == 0 && t >= 1) {
            float part = 0.f;
            const int kb = w * 64;
            #pragma unroll 8
            for (int j = 0; j < 64; ++j)
                part = fmaf(hs[(kb + j) * 64 + b], dW[kb + j], part);
            sred[w * 64 + b] = part;
            __syncthreads();
            if (tid < 64) {
                float dot = db;
                #pragma unroll
                for (int q = 0; q < 8; ++q) dot += sred[q * 64 + tid];
                selp[tid * T_ + (t - 1)] = (dot > 0.f) ? 1 : 0;
            }
        }

        // ---- gates + publish h(t+1) ----
        if (!(SEL && t == T_)) {
            const float ir = pgR, iz = pgZ, in_ = pgN;
            // prefetch gi(t+1) (normal cached loads; drained at arrive)
            if (t + 1 < GI_N) {
                if (SEL) {
                    const float* gb = giF + ((size_t)b * T_ + t + 1) * G_;
                    pgR = gb[i]; pgZ = gb[H_ + i]; pgN = gb[2 * H_ + i];
                } else {
                    const __hip_bfloat16* gb = giB + ((size_t)b * T_ + t + 1) * G_;
                    pgR = __bfloat162float(gb[i]);
                    pgZ = __bfloat162float(gb[H_ + i]);
                    pgN = __bfloat162float(gb[2 * H_ + i]);
                }
            }
            const float hp = hs[i * 64 + b];
            const float r = 1.f / (1.f + expf(-(ir + aR)));
            const float z = 1.f / (1.f + expf(-(iz + aZ)));
            const float n = tanhf(in_ + r * aN);
            float hn = (1.f - z) * n + z * hp;
            if (!SEL) {
                if (t < ns) outp[((size_t)b * T_ + t) * H_ + i] = hn;
                else hn = hp;
            }
            const float* hdst = hnxt + (size_t)i * 64 + b;
            asm volatile("global_store_dword %0, %1, off sc0 sc1"
                         :: "v"(hdst), "v"(hn) : "memory");
        }

        // ---- arrive: drain stores, then publish flag ----
        if (t + 1 < TOTAL) {
            asm volatile("s_waitcnt vmcnt(0)" ::: "memory");
            __syncthreads();
            if (tid == 0) {
                int pv = t + 1;
                asm volatile("global_store_dword %0, %1, off sc0 sc1"
                             :: "v"(flags + bx), "v"(pv) : "memory");
            }
        }
    }
}

// =====================================================================
// Per-batch selection post-processing (unchanged).
// =====================================================================
__global__ void build_order_k(const int* __restrict__ mask, const int* __restrict__ sel,
                              int* __restrict__ order, int* __restrict__ nsel,
                              int* __restrict__ maxn)
{
    const int b = threadIdx.x;
    int lens = 0;
    for (int t = 0; t < T_; ++t) lens += (mask[b * T_ + t] != 0);
    int cnt = 0;
    for (int t = 0; t < T_; ++t) {
        int s = sel[b * T_ + t];
        if (t == 0) s = 1;
        if (t == lens - 1) s = 1;
        if (t >= lens) s = 0;
        if (s) order[b * T_ + (cnt++)] = t;
    }
    nsel[b] = cnt;
    int c2 = cnt;
    for (int t = 0; t < T_; ++t) {
        int s = sel[b * T_ + t];
        if (t == 0) s = 1;
        if (t == lens - 1) s = 1;
        if (t >= lens) s = 0;
        if (!s) order[b * T_ + (c2++)] = t;
    }
    __shared__ int red[64];
    red[b] = cnt;
    __syncthreads();
    if (b == 0) {
        int m = 0;
        for (int q = 0; q < 64; ++q) m = max(m, red[q]);
        *maxn = m;
    }
}

// =====================================================================
// Final linear (unchanged).
// =====================================================================
__global__ void final_k(const unsigned int* __restrict__ pool,
                        const float* __restrict__ Wo, const float* __restrict__ bo,
                        float* __restrict__ out)
{
    const int b = threadIdx.x;
    float s = bo[0];
    for (int f = 0; f < 3 * NF_; ++f)
        s = fmaf(__uint_as_float(pool[b * (3*NF_) + f]), Wo[f], s);
    out[b] = s;
}

// =====================================================================
extern "C" void kernel_launch(void* const* d_in, const int* in_sizes, int n_in,
                              void* d_out, int out_size, void* d_ws, size_t ws_size,
                              hipStream_t stream)
{
    (void)in_sizes; (void)n_in; (void)out_size;
    const float* emb   = (const float*)d_in[0];
    const int*   mask  = (const int*)d_in[1];
    const float* Wih_c = (const float*)d_in[2];
    const float* Whh_c = (const float*)d_in[3];
    const float* bih_c = (const float*)d_in[4];
    const float* bhh_c = (const float*)d_in[5];
    const float* Ws    = (const float*)d_in[6];
    const float* bs    = (const float*)d_in[7];
    const float* Wih0  = (const float*)d_in[8];
    const float* Whh0  = (const float*)d_in[9];
    const float* bih0  = (const float*)d_in[10];
    const float* bhh0  = (const float*)d_in[11];
    const float* Wih1  = (const float*)d_in[12];
    const float* Whh1  = (const float*)d_in[13];
    const float* bih1  = (const float*)d_in[14];
    const float* bhh1  = (const float*)d_in[15];
    const float* Wc3   = (const float*)d_in[16];
    const float* bc3   = (const float*)d_in[17];
    const float* Wc4   = (const float*)d_in[18];
    const float* bc4   = (const float*)d_in[19];
    const float* Wc5   = (const float*)d_in[20];
    const float* bc5   = (const float*)d_in[21];
    const float* Wo    = (const float*)d_in[22];
    const float* bo    = (const float*)d_in[23];

    if (ws_size < WS_NEED) return;
    char* ws = (char*)d_ws;
    float*          giC    = (float*)(ws + OFF_GI);
    __hip_bfloat16* giB    = (__hip_bfloat16*)(ws + OFF_GI);
    float*          outbuf = (float*)(ws + OFF_OUT);
    float*          h0     = (float*)(ws + OFF_H0);
    float*          h1     = (float*)(ws + OFF_H1);
    int*            sel    = (int*)(ws + OFF_SEL);
    int*            order  = (int*)(ws + OFF_ORD);
    int*            nsel   = (int*)(ws + OFF_NSEL);
    int*            maxn   = (int*)(ws + OFF_MAXN);
    int*            flags  = (int*)(ws + OFF_FLG);
    unsigned int*   pool   = (unsigned int*)(ws + OFF_POOL);

    // 1. gi_c = emb @ Wih_c^T + bih_c  (fp32 — argmax precision)
    gemm_k<0,0><<<dim3(512, 24), 256, 0, stream>>>(emb, Wih_c, bih_c, giC, nullptr, nullptr,
                                                   G_, E_, E_, 0, 0, nullptr, nullptr, 0);
    // 2. selector recurrence -> sel
    hipMemsetAsync(flags, 0, 256, stream);
    hipMemsetAsync(h0, 0, (size_t)B_ * H_ * 4, stream);
    rec_k<true><<<64, 512, 0, stream>>>(giC, nullptr, Whh_c, bhh_c, Ws, bs, nullptr, nullptr,
                                        h0, h1, nullptr, sel, flags);
    // 3. forcing + stable partition
    build_order_k<<<1, 64, 0, stream>>>(mask, sel, order, nsel, maxn);
    // 4. gi0 = new_emb @ Wih0^T + bih0 (gathered rows, bf16 out)
    gemm_k<1,1><<<dim3(512, 24), 256, 0, stream>>>(emb, Wih0, bih0, nullptr, giB, nullptr,
                                                   G_, E_, E_, T_, 8, order, nsel, 0);
    // 5. layer0 recurrence -> out0
    hipMemsetAsync(flags, 0, 256, stream);
    hipMemsetAsync(h0, 0, (size_t)B_ * H_ * 4, stream);
    hipMemsetAsync(outbuf, 0, (size_t)B_ * T_ * H_ * 4, stream);
    rec_k<false><<<64, 512, 0, stream>>>(nullptr, giB, Whh0, bhh0, nullptr, nullptr, nsel, maxn,
                                         h0, h1, outbuf, nullptr, flags);
    // 6. gi1 = out0 @ Wih1^T + bih1 (bf16 out)
    gemm_k<0,1><<<dim3(512, 24), 256, 0, stream>>>(outbuf, Wih1, bih1, nullptr, giB, nullptr,
                                                   G_, H_, H_, 0, 0, nullptr, nullptr, 0);
    // 7. layer1 recurrence -> out1 (overwrites out0)
    hipMemsetAsync(flags, 0, 256, stream);
    hipMemsetAsync(h0, 0, (size_t)B_ * H_ * 4, stream);
    hipMemsetAsync(outbuf, 0, (size_t)B_ * T_ * H_ * 4, stream);
    rec_k<false><<<64, 512, 0, stream>>>(nullptr, giB, Whh1, bhh1, nullptr, nullptr, nsel, maxn,
                                         h0, h1, outbuf, nullptr, flags);
    // 8. convs (sliding-window GEMM) + relu + time-max pooling
    hipMemsetAsync(pool, 0, (size_t)B_ * 3 * NF_ * 4, stream);
    gemm_k<2,2><<<dim3(512, 4), 256, 0, stream>>>(outbuf, Wc3, bc3, nullptr, nullptr, pool,
                                                  NF_, 3 * H_, H_, 510, 8, nullptr, nullptr, 0);
    gemm_k<2,2><<<dim3(512, 4), 256, 0, stream>>>(outbuf, Wc4, bc4, nullptr, nullptr, pool,
                                                  NF_, 4 * H_, H_, 509, 8, nullptr, nullptr, 256);
    gemm_k<2,2><<<dim3(512, 4), 256, 0, stream>>>(outbuf, Wc5, bc5, nullptr, nullptr, pool,
                                                  NF_, 5 * H_, H_, 508, 8, nullptr, nullptr, 512);
    // 9. final linear -> d_out (64 f32)
    final_k<<<1, 64, 0, stream>>>(pool, Wo, bo, (float*)d_out);
}